// Round 1
// baseline (61.115 us; speedup 1.0000x reference)
//
#include <hip/hip_runtime.h>

// Debayer 3x3 (bilinear demosaic), B=8, H=1088, W=1920, fp32.
// Output (B,3,H,W). Stencil selection per (ch, y&1, x&1):
//   R: (0,0)->c0 (0,1)->c3 (1,0)->c4 (1,1)->c2
//   G: (0,0)->c1 (0,1)->c0 (1,0)->c0 (1,1)->c1
//   B: (0,0)->c2 (0,1)->c4 (1,0)->c3 (1,1)->c0
// c0=center, c1=0.25*plus4, c2=0.25*diag4, c3=0.5*(L+R), c4=0.5*(U+D)

#define IMG_W 1920
#define IMG_H 1088
#define IMG_B 8

__global__ __launch_bounds__(256) void debayer3x3_kernel(
    const float* __restrict__ x, float* __restrict__ out)
{
    const int WQ = IMG_W / 4;
    const int xq = blockIdx.x * blockDim.x + threadIdx.x;  // quad (4-pixel) index
    if (xq >= WQ) return;
    const int y = blockIdx.y;
    const int b = blockIdx.z;
    const int x0 = xq * 4;

    const float* in = x + (size_t)b * IMG_H * IMG_W;
    const int ym = (y == 0) ? 0 : y - 1;
    const int yp = (y == IMG_H - 1) ? y : y + 1;

    const float* row0 = in + (size_t)ym * IMG_W;
    const float* row1 = in + (size_t)y  * IMG_W;
    const float* row2 = in + (size_t)yp * IMG_W;

    const int xm = (x0 == 0) ? 0 : x0 - 1;                 // left edge clamp
    const int xp = (x0 + 4 >= IMG_W) ? IMG_W - 1 : x0 + 4; // right edge clamp

    // local windows: index j corresponds to image x = x0 - 1 + j, j in [0,6)
    float r0[6], r1[6], r2[6];
    const float4 v0 = *reinterpret_cast<const float4*>(row0 + x0);
    const float4 v1 = *reinterpret_cast<const float4*>(row1 + x0);
    const float4 v2 = *reinterpret_cast<const float4*>(row2 + x0);
    r0[0]=row0[xm]; r0[1]=v0.x; r0[2]=v0.y; r0[3]=v0.z; r0[4]=v0.w; r0[5]=row0[xp];
    r1[0]=row1[xm]; r1[1]=v1.x; r1[2]=v1.y; r1[3]=v1.z; r1[4]=v1.w; r1[5]=row1[xp];
    r2[0]=row2[xm]; r2[1]=v2.x; r2[2]=v2.y; r2[3]=v2.z; r2[4]=v2.w; r2[5]=row2[xp];

    float R[4], G[4], Bv[4];
    const int py = y & 1;  // uniform across the block (blockIdx.y)
    #pragma unroll
    for (int i = 0; i < 4; ++i) {
        const float c0 = r1[i+1];
        const float c1 = 0.25f * (r0[i+1] + r2[i+1] + r1[i] + r1[i+2]);
        const float c2 = 0.25f * (r0[i]   + r0[i+2] + r2[i] + r2[i+2]);
        const float c3 = 0.5f  * (r1[i]   + r1[i+2]);
        const float c4 = 0.5f  * (r0[i+1] + r2[i+1]);
        // x0 is a multiple of 4, so pixel parity is i&1 (compile-time under unroll)
        if ((i & 1) == 0) {
            if (py == 0) { R[i] = c0; G[i] = c1; Bv[i] = c2; }
            else         { R[i] = c4; G[i] = c0; Bv[i] = c3; }
        } else {
            if (py == 0) { R[i] = c3; G[i] = c0; Bv[i] = c4; }
            else         { R[i] = c2; G[i] = c1; Bv[i] = c0; }
        }
    }

    float* outb = out + (size_t)b * 3 * IMG_H * IMG_W;
    const size_t off = (size_t)y * IMG_W + x0;
    *reinterpret_cast<float4*>(outb + off) =
        make_float4(R[0], R[1], R[2], R[3]);
    *reinterpret_cast<float4*>(outb + (size_t)IMG_H * IMG_W + off) =
        make_float4(G[0], G[1], G[2], G[3]);
    *reinterpret_cast<float4*>(outb + 2 * (size_t)IMG_H * IMG_W + off) =
        make_float4(Bv[0], Bv[1], Bv[2], Bv[3]);
}

extern "C" void kernel_launch(void* const* d_in, const int* in_sizes, int n_in,
                              void* d_out, int out_size, void* d_ws, size_t ws_size,
                              hipStream_t stream) {
    const float* x = (const float*)d_in[0];
    float* out = (float*)d_out;

    const int WQ = IMG_W / 4;                 // 480
    dim3 block(256, 1, 1);
    dim3 grid((WQ + 255) / 256, IMG_H, IMG_B); // (2, 1088, 8)
    debayer3x3_kernel<<<grid, block, 0, stream>>>(x, out);
}

// Round 3
// 47.077 us; speedup vs baseline: 1.2982x; 1.2982x over previous
//
#include <hip/hip_runtime.h>

// Debayer 3x3 (bilinear demosaic), B=8, H=1088, W=1920, fp32 -> (B,3,H,W).
// Stencils: c0=center, c1=0.25*plus4, c2=0.25*diag4, c3=0.5*(L+R), c4=0.5*(U+D)
// Selection by (y&1, x&1):
//   (0,0): R=c0 G=c1 B=c2   (0,1): R=c3 G=c0 B=c4
//   (1,0): R=c4 G=c0 B=c3   (1,1): R=c2 G=c1 B=c0
//
// Each thread: one 4-pixel quad (float4-aligned) x 8 consecutive rows, with a
// rolling 3-row x 6-wide register window. Vertical halo reuse happens in
// registers (1.25x fetch instead of 3x cross-XCD L2 misses).

#define IMG_W 1920
#define IMG_H 1088
#define IMG_B 8
#define ROWS 8
#define WQ (IMG_W / 4)        // 480
#define GROUPS (IMG_H / ROWS) // 136

typedef float vfloat4 __attribute__((ext_vector_type(4)));  // native vector for nontemporal builtin

__device__ __forceinline__ void load_row6(const float* __restrict__ row,
                                          int x0, int xm, int xp, float w[6]) {
    const vfloat4 v = *reinterpret_cast<const vfloat4*>(row + x0);
    w[0] = row[xm]; w[1] = v.x; w[2] = v.y; w[3] = v.z; w[4] = v.w; w[5] = row[xp];
}

__global__ __launch_bounds__(256) void debayer_kernel(const float* __restrict__ x,
                                                      float* __restrict__ out) {
    const int tid = blockIdx.x * 256 + threadIdx.x;   // grid is exact: no bounds check
    const int xq  = tid % WQ;
    const int g   = tid / WQ;
    const int grp = g % GROUPS;
    const int b   = g / GROUPS;

    const int x0 = xq * 4;
    const int xm = (x0 == 0) ? 0 : x0 - 1;                  // left edge clamp
    const int xp = (x0 + 4 >= IMG_W) ? IMG_W - 1 : x0 + 4;  // right edge clamp
    const int y0 = grp * ROWS;                              // always even -> parity = r&1

    const float* in = x + (size_t)b * IMG_H * IMG_W;
    float* outb = out + (size_t)b * 3 * IMG_H * IMG_W;

    float win[3][6];
    load_row6(in + (size_t)((y0 == 0) ? 0 : y0 - 1) * IMG_W, x0, xm, xp, win[0]);
    load_row6(in + (size_t)y0 * IMG_W, x0, xm, xp, win[1]);

    #pragma unroll
    for (int r = 0; r < ROWS; ++r) {
        const int yn = y0 + r + 1;
        load_row6(in + (size_t)((yn > IMG_H - 1) ? IMG_H - 1 : yn) * IMG_W,
                  x0, xm, xp, win[(r + 2) % 3]);
        const float* a = win[r % 3];        // row y-1
        const float* m = win[(r + 1) % 3];  // row y
        const float* c = win[(r + 2) % 3];  // row y+1

        float R[4], G[4], Bl[4];
        #pragma unroll
        for (int i = 0; i < 4; ++i) {
            const float c0 = m[i + 1];
            const float c1 = 0.25f * (a[i + 1] + c[i + 1] + m[i] + m[i + 2]);
            const float c2 = 0.25f * (a[i] + a[i + 2] + c[i] + c[i + 2]);
            const float c3 = 0.5f  * (m[i] + m[i + 2]);
            const float c4 = 0.5f  * (a[i + 1] + c[i + 1]);
            const int py = r & 1;  // compile-time under unroll
            const int px = i & 1;  // compile-time under unroll
            if (py == 0) {
                if (px == 0) { R[i] = c0; G[i] = c1; Bl[i] = c2; }
                else         { R[i] = c3; G[i] = c0; Bl[i] = c4; }
            } else {
                if (px == 0) { R[i] = c4; G[i] = c0; Bl[i] = c3; }
                else         { R[i] = c2; G[i] = c1; Bl[i] = c0; }
            }
        }

        const size_t off = (size_t)(y0 + r) * IMG_W + x0;
        vfloat4 vr = {R[0], R[1], R[2], R[3]};
        vfloat4 vg = {G[0], G[1], G[2], G[3]};
        vfloat4 vb = {Bl[0], Bl[1], Bl[2], Bl[3]};
        __builtin_nontemporal_store(vr, reinterpret_cast<vfloat4*>(outb + off));
        __builtin_nontemporal_store(vg, reinterpret_cast<vfloat4*>(outb + (size_t)IMG_H * IMG_W + off));
        __builtin_nontemporal_store(vb, reinterpret_cast<vfloat4*>(outb + 2 * (size_t)IMG_H * IMG_W + off));
    }
}

extern "C" void kernel_launch(void* const* d_in, const int* in_sizes, int n_in,
                              void* d_out, int out_size, void* d_ws, size_t ws_size,
                              hipStream_t stream) {
    const float* x = (const float*)d_in[0];
    float* out = (float*)d_out;

    const int total = WQ * GROUPS * IMG_B;     // 522240
    dim3 block(256, 1, 1);
    dim3 grid(total / 256, 1, 1);              // 2040 blocks, exact
    debayer_kernel<<<grid, block, 0, stream>>>(x, out);
}

// Round 4
// 43.665 us; speedup vs baseline: 1.3996x; 1.0781x over previous
//
#include <hip/hip_runtime.h>

// Debayer 3x3 (bilinear demosaic), B=8, H=1088, W=1920, fp32 -> (B,3,H,W).
// Stencils: c0=center, c1=0.25*plus4, c2=0.25*diag4, c3=0.5*(L+R), c4=0.5*(U+D)
// Selection by (y&1, x&1):
//   (0,0): R=c0 G=c1 B=c2   (0,1): R=c3 G=c0 B=c4
//   (1,0): R=c4 G=c0 B=c3   (1,1): R=c2 G=c1 B=c0
//
// Thread = one 4-px quad x 8 rows, rolling 3x6 register window (vertical reuse
// in registers). XCD swizzle: 2040 blocks = 8 XCDs x 255; each XCD owns one
// batch image so inter-group halo rows hit the same XCD's L2.

#define IMG_W 1920
#define IMG_H 1088
#define IMG_B 8
#define ROWS 8
#define WQ (IMG_W / 4)        // 480
#define GROUPS (IMG_H / ROWS) // 136
#define NBLOCKS (WQ * GROUPS * IMG_B / 256)  // 2040
#define BLKS_PER_XCD (NBLOCKS / 8)           // 255

typedef float vfloat4 __attribute__((ext_vector_type(4)));

__device__ __forceinline__ void load_row6(const float* __restrict__ row,
                                          int x0, int xm, int xp, float w[6]) {
    const vfloat4 v = *reinterpret_cast<const vfloat4*>(row + x0);
    w[0] = row[xm]; w[1] = v.x; w[2] = v.y; w[3] = v.z; w[4] = v.w; w[5] = row[xp];
}

__global__ __launch_bounds__(256) void debayer_kernel(const float* __restrict__ x,
                                                      float* __restrict__ out) {
    // XCD-aware swizzle: consecutive hardware dispatch (bid % 8 = XCD) maps to
    // contiguous work chunks per XCD. Bijective since NBLOCKS % 8 == 0.
    const int bid = (int)blockIdx.x;
    const int sbid = (bid & 7) * BLKS_PER_XCD + (bid >> 3);
    const int tid = sbid * 256 + (int)threadIdx.x;

    const int xq  = tid % WQ;
    const int g   = tid / WQ;
    const int grp = g % GROUPS;
    const int b   = g / GROUPS;

    const int x0 = xq * 4;
    const int xm = (x0 == 0) ? 0 : x0 - 1;                  // left edge clamp
    const int xp = (x0 + 4 >= IMG_W) ? IMG_W - 1 : x0 + 4;  // right edge clamp
    const int y0 = grp * ROWS;                              // even -> parity = r&1

    const float* in = x + (size_t)b * IMG_H * IMG_W;
    float* outb = out + (size_t)b * 3 * IMG_H * IMG_W;

    float win[3][6];
    load_row6(in + (size_t)((y0 == 0) ? 0 : y0 - 1) * IMG_W, x0, xm, xp, win[0]);
    load_row6(in + (size_t)y0 * IMG_W, x0, xm, xp, win[1]);

    #pragma unroll
    for (int r = 0; r < ROWS; ++r) {
        const int yn = y0 + r + 1;
        load_row6(in + (size_t)((yn > IMG_H - 1) ? IMG_H - 1 : yn) * IMG_W,
                  x0, xm, xp, win[(r + 2) % 3]);
        const float* a = win[r % 3];        // row y-1
        const float* m = win[(r + 1) % 3];  // row y
        const float* c = win[(r + 2) % 3];  // row y+1

        float R[4], G[4], Bl[4];
        #pragma unroll
        for (int i = 0; i < 4; ++i) {
            const float c0 = m[i + 1];
            const float c1 = 0.25f * (a[i + 1] + c[i + 1] + m[i] + m[i + 2]);
            const float c2 = 0.25f * (a[i] + a[i + 2] + c[i] + c[i + 2]);
            const float c3 = 0.5f  * (m[i] + m[i + 2]);
            const float c4 = 0.5f  * (a[i + 1] + c[i + 1]);
            const int py = r & 1;  // compile-time under unroll
            const int px = i & 1;  // compile-time under unroll
            if (py == 0) {
                if (px == 0) { R[i] = c0; G[i] = c1; Bl[i] = c2; }
                else         { R[i] = c3; G[i] = c0; Bl[i] = c4; }
            } else {
                if (px == 0) { R[i] = c4; G[i] = c0; Bl[i] = c3; }
                else         { R[i] = c2; G[i] = c1; Bl[i] = c0; }
            }
        }

        const size_t off = (size_t)(y0 + r) * IMG_W + x0;
        vfloat4 vr = {R[0], R[1], R[2], R[3]};
        vfloat4 vg = {G[0], G[1], G[2], G[3]};
        vfloat4 vb = {Bl[0], Bl[1], Bl[2], Bl[3]};
        __builtin_nontemporal_store(vr, reinterpret_cast<vfloat4*>(outb + off));
        __builtin_nontemporal_store(vg, reinterpret_cast<vfloat4*>(outb + (size_t)IMG_H * IMG_W + off));
        __builtin_nontemporal_store(vb, reinterpret_cast<vfloat4*>(outb + 2 * (size_t)IMG_H * IMG_W + off));
    }
}

extern "C" void kernel_launch(void* const* d_in, const int* in_sizes, int n_in,
                              void* d_out, int out_size, void* d_ws, size_t ws_size,
                              hipStream_t stream) {
    const float* x = (const float*)d_in[0];
    float* out = (float*)d_out;

    dim3 block(256, 1, 1);
    dim3 grid(NBLOCKS, 1, 1);  // 2040 blocks, exact cover
    debayer_kernel<<<grid, block, 0, stream>>>(x, out);
}